// Round 16
// baseline (1830.728 us; speedup 1.0000x reference)
//
#include <hip/hip_runtime.h>
#include <math.h>

// Dims fixed: T=4, B=8, C=128, H=W=56, mid=128.
#define T_ 4
#define B_ 8
#define C_ 128
#define H_ 56
#define W_ 56
#define NIMG (T_ * B_)              // 32
#define HW (H_ * W_)                // 3136
#define NLOC ((size_t)B_ * C_ * HW) // 3211264 per-t elements
#define NE ((size_t)T_ * NLOC)      // 12845056
#define ROWP 7168                   // 56px * 128B per A row
#define ABUFSZ (4 * ROWP)           // 28672: rows h0-1..h0+2 for one t

typedef __attribute__((ext_vector_type(4))) int   int4v;
typedef __attribute__((ext_vector_type(4))) float float4v;

#define GLOAD_LDS16(gp, lp) \
    __builtin_amdgcn_global_load_lds((const __attribute__((address_space(1))) unsigned int*)(gp), \
                                     (__attribute__((address_space(3))) unsigned int*)(lp), 16, 0, 0)

#define MFMA_I8 __builtin_amdgcn_mfma_i32_16x16x64_i8

// ---------------------------------------------------------------------------
// per-co scale: sv[co] = max_{ci,tap}|w[co][ci][tap]| / 127
// ---------------------------------------------------------------------------
__global__ __launch_bounds__(128) void scale_k(const float* __restrict__ w,
                                               float* __restrict__ sv) {
    __shared__ float red[128];
    int co = blockIdx.x, t = threadIdx.x;
    const float* p = w + (size_t)co * 1152 + t * 9;
    float m = 0.f;
#pragma unroll
    for (int j = 0; j < 9; ++j) m = fmaxf(m, fabsf(p[j]));
    red[t] = m; __syncthreads();
    for (int off = 64; off; off >>= 1) {
        if (t < off) red[t] = fmaxf(red[t], red[t + off]);
        __syncthreads();
    }
    if (t == 0) sv[co] = fmaxf(red[0], 1e-20f) / 127.f;
}

// ---------------------------------------------------------------------------
// repack weights -> 27 i8 tiles of 16KB (tile = tap*3 + split), LDS-DMA layout:
// tile byte L(co,ci) = co*128 + ((ci>>4 ^ (co&7))<<4) + (ci&15)
// 3-way split: w = s*(q1 + q2/128 + q3/16384), exact-int accumulation.
// ---------------------------------------------------------------------------
__global__ __launch_bounds__(256) void repack_k(const float* __restrict__ w,
                                                const float* __restrict__ sv,
                                                signed char* __restrict__ Bs) {
    int idx = blockIdx.x * 256 + threadIdx.x;
    if (idx >= 9 * 1024) return;
    int tap = idx >> 10;
    int rem = idx & 1023;
    int co = rem >> 3, cig = rem & 7;
    double s = (double)sv[co];
    union { signed char b[16]; int4v v; } q[3];
#pragma unroll
    for (int e = 0; e < 16; ++e) {
        int ci = cig * 16 + e;
        double v = (double)w[((size_t)co * 128 + ci) * 9 + tap];
        double q1 = rint(v / s);
        double r1 = v - s * q1;
        double q2 = rint(r1 * 128.0 / s);
        double r2 = r1 - s * q2 * 0.0078125;
        double q3 = rint(r2 * 16384.0 / s);
        q[0].b[e] = (signed char)(int)q1;
        q[1].b[e] = (signed char)(int)q2;
        q[2].b[e] = (signed char)(int)q3;
    }
    int Lb = co * 128 + ((cig ^ (co & 7)) << 4);
#pragma unroll
    for (int sp = 0; sp < 3; ++sp)
        *(int4v*)(Bs + (size_t)(tap * 3 + sp) * 16384 + Lb) = q[sp].v;
}

// ---------------------------------------------------------------------------
// x fp32 NCHW -> Xt i8 NHWC, ci-slot XOR-swizzled by (w&7)
// ---------------------------------------------------------------------------
__global__ __launch_bounds__(256) void xpose_k(const float* __restrict__ x,
                                               signed char* __restrict__ Xt) {
    __shared__ float xs[128][57];
    int n = blockIdx.x / 56, h = blockIdx.x % 56;
    int tid = threadIdx.x;
    const float* xp = x + (size_t)n * 128 * HW + h * 56;
#pragma unroll
    for (int j = 0; j < 7; ++j) {
        int idx = tid + j * 256;              // 0..1791 = c*14 + wq
        int c = idx / 14, wq = idx - c * 14;
        float4 v = *(const float4*)(xp + (size_t)c * HW + wq * 4);
        xs[c][wq * 4 + 0] = v.x; xs[c][wq * 4 + 1] = v.y;
        xs[c][wq * 4 + 2] = v.z; xs[c][wq * 4 + 3] = v.w;
    }
    __syncthreads();
    signed char* Op = Xt + ((size_t)n * HW + h * 56) * 128;
#pragma unroll
    for (int j = 0; j < 2; ++j) {
        int idx = tid + j * 256;              // 0..447 = ww*8 + slot
        if (idx < 448) {
            int ww = idx >> 3, sl = idx & 7;
            int cg = sl ^ (ww & 7);
            union { signed char b[16]; int4v v; } u;
#pragma unroll
            for (int e = 0; e < 16; ++e)
                u.b[e] = (xs[cg * 16 + e][ww] >= 0.5f) ? 1 : 0;
            *(int4v*)(Op + ww * 128 + sl * 16) = u.v;
        }
    }
}

// ---------------------------------------------------------------------------
// Fused conv3x3 SAME + BN + PLIF (+residual), i8 MFMA implicit GEMM.
// Block = (b, row-pair): 512 thr / 8 waves = 2 rows x 4 co-quarters.
// NEW: t processed in PAIRS {0,1},{2,3}. Per pair, each 48KB tap-tile staged
// ONCE and consumed for both t (B-DMA halved: 1.73MB->0.86MB per block);
// 96 MFMA per barrier-period. Exact int per (tap,sp), fp32 fold per tap
// (power-of-2 split weights -> exact mults; R3-class rounding, passed).
// A: both t's resident (2x28KB). B dbuf 2x48KB. LDS 152KB, 1 block/CU.
// MODE 0: spikes i8 NHWC swizzled.  MODE 1: spike + x, fp32 NCHW.
// ---------------------------------------------------------------------------
template<int MODE>
__global__ __launch_bounds__(512, 2) void convplif_k(
        const signed char* __restrict__ Xin,  // i8 NHWC swizzled [32][3136][128]
        const signed char* __restrict__ Bs,   // 27 x 16KB tiles (tap*3+sp)
        const float* __restrict__ sv,
        const float* __restrict__ gamma, const float* __restrict__ beta,
        const float* __restrict__ mean,  const float* __restrict__ var,
        const float* __restrict__ tau,
        const float* __restrict__ xres,       // MODE1: residual input x
        void* __restrict__ outp) {
    __shared__ signed char aA[2 * ABUFSZ];    // A: t-pair slots (4 rows each)
    __shared__ signed char bB[2 * 49152];     // B tap dbuf (3 split tiles each)
    // sS (MODE0 spike scratch, 16KB) aliases bB+49152 (dead at epilogue time)

    const int tid = threadIdx.x;
    const int lane = tid & 63;
    const int wave = tid >> 6;
    const int fr = lane & 15, fq = lane >> 4;
    const int row_local = wave >> 2;          // 0..1
    const int q = wave & 3;                   // co-quarter
    const int bb = blockIdx.x / 28;
    const int h0 = (blockIdx.x % 28) * 2;
    const int h = h0 + row_local;

    const float kk = 1.f / (1.f + expf(-tau[0]));
    float mulv[2], bsv[2];
#pragma unroll
    for (int nf = 0; nf < 2; ++nf) {
        int co = q * 32 + nf * 16 + fr;
        float iv = gamma[co] / sqrtf(var[co] + 1e-5f);
        mulv[nf] = sv[co] * iv;
        bsv[nf] = beta[co] - mean[co] * iv;
    }

    int vb0, vb1;
    {
        int cob = (q * 32 + fr) * 128;
        int sl0 = (fq ^ (fr & 7)) << 4;
        vb0 = cob + sl0;
        vb1 = cob + (sl0 ^ 64);               // ks=1 slot
    }

    const int4v zi = (int4v){0, 0, 0, 0};

    // A stage for one t into slot S: 4 rows x 448 chunks = 1792; every thread
    // issues exactly 4 (overflow/invalid-row remapped to row1 dup -> uniform).
#define STAGEA(tt, S) do {                                                        \
        const signed char* _XtN = Xin + (size_t)((tt) * 8 + bb) * (HW * 128);     \
        _Pragma("unroll")                                                         \
        for (int _i = 0; _i < 4; ++_i) {                                          \
            int _idx = tid + _i * 512;                                            \
            int _row = _idx < 1792 ? _idx / 448 : 1;                              \
            int _off = _idx < 1792 ? _idx - _row * 448 : _idx - 1792;             \
            int _hh = h0 - 1 + _row;                                              \
            if ((unsigned)_hh >= 56u) { _row = 1; _hh = h0; }                     \
            GLOAD_LDS16((const char*)(_XtN + (size_t)_hh * ROWP) + _off * 16,     \
                        (char*)aA + (S) * ABUFSZ + _row * ROWP + _off * 16);      \
        }                                                                         \
    } while (0)

    // stage one tap's 3 split tiles (48KB) into B buffer BUF: 6 instr/thread
#define STB(TAP, BUF) do {                                                        \
        const char* _s = (const char*)Bs + (size_t)(TAP) * 49152 + tid * 16;      \
        char* _d = (char*)bB + (BUF) * 49152 + tid * 16;                          \
        _Pragma("unroll")                                                         \
        for (int _c = 0; _c < 6; ++_c)                                            \
            GLOAD_LDS16(_s + _c * 8192, _d + _c * 8192);                          \
    } while (0)

    // ---- prologue: A(t0)->slot0, A(t1)->slot1, tap0->buf0 ----
    STAGEA(0, 0);
    STAGEA(1, 1);
    STB(0, 0);
    asm volatile("s_waitcnt vmcnt(0) lgkmcnt(0)" ::: "memory");
    __builtin_amdgcn_sched_barrier(0);
    __builtin_amdgcn_s_barrier();

    float4v facc[2][4][2];                    // [t01][m][nf] fp32 accum
    float v[2][4][4];                         // PLIF state [nf][m][r]
#pragma unroll
    for (int nf = 0; nf < 2; ++nf)
#pragma unroll
        for (int m = 0; m < 4; ++m)
#pragma unroll
            for (int r = 0; r < 4; ++r) v[nf][m][r] = 0.f;

    for (int pair = 0; pair < 2; ++pair) {
#pragma unroll
        for (int t01 = 0; t01 < 2; ++t01)
#pragma unroll
            for (int m = 0; m < 4; ++m) {
                facc[t01][m][0] = (float4v){0.f, 0.f, 0.f, 0.f};
                facc[t01][m][1] = (float4v){0.f, 0.f, 0.f, 0.f};
            }

        // ---- 9 tap-periods (unrolled; tap compile-time) ----
#define CLT(T01, DH, DW, BUF) do {                                                \
            const bool _hok = ((unsigned)(h + (DH) - 1) < 56u);                   \
            const char* _ab = (char*)aA + (T01) * ABUFSZ + ((DH)) * 0            \
                              + (row_local + (DH)) * ROWP + (T01) * 0;            \
            int4v a[4][2];                                                        \
            _Pragma("unroll")                                                     \
            for (int _m = 0; _m < 4; ++_m) {                                      \
                int _px = _m * 16 + fr + (DW) - 1;                                \
                bool _ok = _hok && ((unsigned)_px < 56u);                         \
                int _pxc = _ok ? _px : 0;                                         \
                int _k7 = _pxc & 7;                                               \
                int4v _a0 = *(const int4v*)(_ab + _pxc * 128 + ((fq ^ _k7) << 4));\
                int4v _a1 = *(const int4v*)(_ab + _pxc * 128 + (((4 + fq) ^ _k7) << 4)); \
                a[_m][0] = _ok ? _a0 : zi;                                        \
                a[_m][1] = _ok ? _a1 : zi;                                        \
            }                                                                     \
            _Pragma("unroll")                                                     \
            for (int _sp = 0; _sp < 3; ++_sp) {                                   \
                const float _w = (_sp == 0) ? 1.0f                                \
                               : (_sp == 1 ? 0.0078125f : 6.103515625e-05f);      \
                const signed char* _bp = (const signed char*)bB                   \
                                       + (BUF) * 49152 + _sp * 16384;             \
                int4v _b0 = *(const int4v*)(_bp + vb0);                           \
                int4v _b1 = *(const int4v*)(_bp + vb1);                           \
                int4v _b2 = *(const int4v*)(_bp + vb0 + 2048);                    \
                int4v _b3 = *(const int4v*)(_bp + vb1 + 2048);                    \
                __builtin_amdgcn_s_setprio(1);                                    \
                _Pragma("unroll")                                                 \
                for (int _m = 0; _m < 4; ++_m) {                                  \
                    int4v _i0 = MFMA_I8(a[_m][0], _b0, zi, 0, 0, 0);              \
                    _i0 = MFMA_I8(a[_m][1], _b1, _i0, 0, 0, 0);                   \
                    int4v _i1 = MFMA_I8(a[_m][0], _b2, zi, 0, 0, 0);              \
                    _i1 = MFMA_I8(a[_m][1], _b3, _i1, 0, 0, 0);                   \
                    facc[T01][_m][0] += __builtin_convertvector(_i0, float4v) * _w; \
                    facc[T01][_m][1] += __builtin_convertvector(_i1, float4v) * _w; \
                }                                                                 \
                __builtin_amdgcn_s_setprio(0);                                    \
            }                                                                     \
        } while (0)

#define PERIOD(P, DH, DW) do {                                                    \
            if ((P) < 8) STB((P) + 1, ((P) + 1) & 1);                             \
            if ((P) == 8) { asm volatile("s_waitcnt vmcnt(0)" ::: "memory"); }    \
            else          { asm volatile("s_waitcnt vmcnt(6)" ::: "memory"); }    \
            __builtin_amdgcn_sched_barrier(0);                                    \
            __builtin_amdgcn_s_barrier();                                         \
            CLT(0, DH, DW, (P) & 1);                                              \
            CLT(1, DH, DW, (P) & 1);                                              \
            asm volatile("s_waitcnt lgkmcnt(0)" ::: "memory");                    \
            __builtin_amdgcn_sched_barrier(0);                                    \
            __builtin_amdgcn_s_barrier();                                         \
        } while (0)

        PERIOD(0, 0, 0); PERIOD(1, 0, 1); PERIOD(2, 0, 2);
        PERIOD(3, 1, 0); PERIOD(4, 1, 1); PERIOD(5, 1, 2);
        PERIOD(6, 2, 0); PERIOD(7, 2, 1); PERIOD(8, 2, 2);

        // ---- pair boundary: aA/bB dead; overlap next-pair staging w/ epilogue
        if (pair == 0) {
            STAGEA(2, 0);
            STAGEA(3, 1);
            STB(0, 0);                         // tap0 for pair 1
        }

        // ---- epilogue for t0,t1 of this pair ----
#pragma unroll
        for (int t01 = 0; t01 < 2; ++t01) {
            const int t = pair * 2 + t01;
            if (MODE == 0) {
                signed char* sS = (signed char*)bB + 49152;   // buf1 (dead)
                signed char* S1 = (signed char*)outp;
#pragma unroll
                for (int nf = 0; nf < 2; ++nf)
#pragma unroll
                    for (int m = 0; m < 4; ++m)
#pragma unroll
                        for (int r = 0; r < 4; ++r) {
                            int px = m * 16 + fq * 4 + r;
                            float y = fmaf(facc[t01][m][nf][r], mulv[nf], bsv[nf]);
                            float vv = v[nf][m][r];
                            vv = vv + (y - vv) * kk;
                            bool spk = vv >= 1.f;
                            v[nf][m][r] = spk ? 0.f : vv;
                            sS[row_local * 8192 + px * 128 + q * 32 + nf * 16 + fr] = spk ? 1 : 0;
                        }
                asm volatile("s_waitcnt lgkmcnt(0)" ::: "memory");
                __builtin_amdgcn_s_barrier();
                const size_t imgb = (size_t)(t * 8 + bb) * HW;
#pragma unroll
                for (int cc = 0; cc < 2; ++cc) {
                    int chunk = tid + cc * 512;
                    int row = chunk >> 9, rem = chunk & 511;
                    int px = rem >> 3, cg = rem & 7;
                    if (px < 56) {
                        int4v v16 = *(const int4v*)(sS + row * 8192 + px * 128 + cg * 16);
                        *(int4v*)(S1 + (imgb + (size_t)(h0 + row) * 56 + px) * 128
                                     + ((cg ^ (px & 7)) << 4)) = v16;
                    }
                }
                asm volatile("s_waitcnt lgkmcnt(0)" ::: "memory");
                __builtin_amdgcn_s_barrier();  // sS reads done before next use
            } else {
                float* outw = (float*)outp;
#pragma unroll
                for (int nf = 0; nf < 2; ++nf) {
                    const size_t cobase = ((size_t)(t * 8 + bb) * 128 + q * 32 + nf * 16 + fr) * HW
                                        + (size_t)h * 56;
#pragma unroll
                    for (int m = 0; m < 4; ++m) {
                        int px0 = m * 16 + fq * 4;
                        float o4[4];
#pragma unroll
                        for (int r = 0; r < 4; ++r) {
                            float y = fmaf(facc[t01][m][nf][r], mulv[nf], bsv[nf]);
                            float vv = v[nf][m][r];
                            vv = vv + (y - vv) * kk;
                            bool spk = vv >= 1.f;
                            v[nf][m][r] = spk ? 0.f : vv;
                            o4[r] = spk ? 1.f : 0.f;
                        }
                        if (px0 < 56) {
                            float4 xv = *(const float4*)(xres + cobase + px0);
                            float4 ov = make_float4(o4[0] + xv.x, o4[1] + xv.y,
                                                    o4[2] + xv.z, o4[3] + xv.w);
                            *(float4*)(outw + cobase + px0) = ov;
                        }
                    }
                }
            }
        }
        if (MODE == 1) __builtin_amdgcn_s_barrier();  // re-align before next pair

        if (pair == 0) {
            // next pair's A + tap0 staged above; drain & rendezvous once
            asm volatile("s_waitcnt vmcnt(0)" ::: "memory");
            __builtin_amdgcn_sched_barrier(0);
            __builtin_amdgcn_s_barrier();
        }
#undef PERIOD
#undef CLT
    }
#undef STB
#undef STAGEA
}

// ---------------------------------------------------------------------------
extern "C" void kernel_launch(void* const* d_in, const int* in_sizes, int n_in,
                              void* d_out, int out_size, void* d_ws, size_t ws_size,
                              hipStream_t stream) {
    const float* x    = (const float*)d_in[0];
    const float* w1   = (const float*)d_in[1];
    const float* g1   = (const float*)d_in[2];
    const float* be1  = (const float*)d_in[3];
    const float* mu1  = (const float*)d_in[4];
    const float* va1  = (const float*)d_in[5];
    const float* tau1 = (const float*)d_in[6];
    const float* w2   = (const float*)d_in[7];
    const float* g2   = (const float*)d_in[8];
    const float* be2  = (const float*)d_in[9];
    const float* mu2  = (const float*)d_in[10];
    const float* va2  = (const float*)d_in[11];
    const float* tau2 = (const float*)d_in[12];
    float* out = (float*)d_out;

    char* ws = (char*)d_ws;
    signed char* Xt  = (signed char*)ws;           // i8 [NE]
    signed char* S1  = (signed char*)(ws + NE);    // i8 [NE]
    float* sv1  = (float*)(ws + 2 * NE);
    float* sv2  = sv1 + 128;
    signed char* Bs1 = (signed char*)(ws + 2 * NE + 1024);
    signed char* Bs2 = Bs1 + 27 * 16384;

    scale_k<<<128, 128, 0, stream>>>(w1, sv1);
    scale_k<<<128, 128, 0, stream>>>(w2, sv2);
    repack_k<<<36, 256, 0, stream>>>(w1, sv1, Bs1);
    repack_k<<<36, 256, 0, stream>>>(w2, sv2, Bs2);
    xpose_k<<<NIMG * 56, 256, 0, stream>>>(x, Xt);

    convplif_k<0><<<B_ * 28, 512, 0, stream>>>(Xt, Bs1, sv1, g1, be1, mu1, va1,
                                               tau1, x, (void*)S1);
    convplif_k<1><<<B_ * 28, 512, 0, stream>>>(S1, Bs2, sv2, g2, be2, mu2, va2,
                                               tau2, x, (void*)out);
}

// Round 17
// 163.127 us; speedup vs baseline: 11.2227x; 11.2227x over previous
//
#include <hip/hip_runtime.h>
#include <math.h>

// Dims fixed: T=4, B=8, C=128, H=W=56, mid=128.
#define T_ 4
#define B_ 8
#define C_ 128
#define H_ 56
#define W_ 56
#define NIMG (T_ * B_)              // 32
#define HW (H_ * W_)                // 3136
#define NLOC ((size_t)B_ * C_ * HW) // 3211264 per-t elements
#define NE ((size_t)T_ * NLOC)      // 12845056
#define APITCH 8448                 // 66 px-slots * 128B (slot0 + slots57..65 zero pad)

typedef __attribute__((ext_vector_type(4))) int   int4v;

#define GLOAD_LDS16(gp, lp) \
    __builtin_amdgcn_global_load_lds((const __attribute__((address_space(1))) unsigned int*)(gp), \
                                     (__attribute__((address_space(3))) unsigned int*)(lp), 16, 0, 0)

// ---------------------------------------------------------------------------
// per-co scale: sv[co] = max_{ci,tap}|w[co][ci][tap]| / 127
// ---------------------------------------------------------------------------
__global__ __launch_bounds__(128) void scale_k(const float* __restrict__ w,
                                               float* __restrict__ sv) {
    __shared__ float red[128];
    int co = blockIdx.x, t = threadIdx.x;
    const float* p = w + (size_t)co * 1152 + t * 9;
    float m = 0.f;
#pragma unroll
    for (int j = 0; j < 9; ++j) m = fmaxf(m, fabsf(p[j]));
    red[t] = m; __syncthreads();
    for (int off = 64; off; off >>= 1) {
        if (t < off) red[t] = fmaxf(red[t], red[t + off]);
        __syncthreads();
    }
    if (t == 0) sv[co] = fmaxf(red[0], 1e-20f) / 127.f;
}

// ---------------------------------------------------------------------------
// repack weights -> 27 i8 tiles of 16KB (stage = tap*3 + split), LDS-DMA layout:
// tile byte L(co,ci) = co*128 + ((ci>>4 ^ (co&7))<<4) + (ci&15)
// 3-way split: w = s*(q1 + q2/128 + q3/16384), exact-int accumulation.
// ---------------------------------------------------------------------------
__global__ __launch_bounds__(256) void repack_k(const float* __restrict__ w,
                                                const float* __restrict__ sv,
                                                signed char* __restrict__ Bs) {
    int idx = blockIdx.x * 256 + threadIdx.x;
    if (idx >= 9 * 1024) return;
    int tap = idx >> 10;
    int rem = idx & 1023;
    int co = rem >> 3, cig = rem & 7;
    double s = (double)sv[co];
    union { signed char b[16]; int4v v; } q[3];
#pragma unroll
    for (int e = 0; e < 16; ++e) {
        int ci = cig * 16 + e;
        double v = (double)w[((size_t)co * 128 + ci) * 9 + tap];
        double q1 = rint(v / s);
        double r1 = v - s * q1;
        double q2 = rint(r1 * 128.0 / s);
        double r2 = r1 - s * q2 * 0.0078125;
        double q3 = rint(r2 * 16384.0 / s);
        q[0].b[e] = (signed char)(int)q1;
        q[1].b[e] = (signed char)(int)q2;
        q[2].b[e] = (signed char)(int)q3;
    }
    int Lb = co * 128 + ((cig ^ (co & 7)) << 4);
#pragma unroll
    for (int sp = 0; sp < 3; ++sp)
        *(int4v*)(Bs + (size_t)(tap * 3 + sp) * 16384 + Lb) = q[sp].v;
}

// ---------------------------------------------------------------------------
// x fp32 NCHW -> Xt i8 NHWC, ci-slot XOR-swizzled by (w&7)
// ---------------------------------------------------------------------------
__global__ __launch_bounds__(256) void xpose_k(const float* __restrict__ x,
                                               signed char* __restrict__ Xt) {
    __shared__ float xs[128][57];
    int n = blockIdx.x / 56, h = blockIdx.x % 56;
    int tid = threadIdx.x;
    const float* xp = x + (size_t)n * 128 * HW + h * 56;
#pragma unroll
    for (int j = 0; j < 7; ++j) {
        int idx = tid + j * 256;              // 0..1791 = c*14 + wq
        int c = idx / 14, wq = idx - c * 14;
        float4 v = *(const float4*)(xp + (size_t)c * HW + wq * 4);
        xs[c][wq * 4 + 0] = v.x; xs[c][wq * 4 + 1] = v.y;
        xs[c][wq * 4 + 2] = v.z; xs[c][wq * 4 + 3] = v.w;
    }
    __syncthreads();
    signed char* Op = Xt + ((size_t)n * HW + h * 56) * 128;
#pragma unroll
    for (int j = 0; j < 2; ++j) {
        int idx = tid + j * 256;              // 0..447 = ww*8 + slot
        if (idx < 448) {
            int ww = idx >> 3, sl = idx & 7;
            int cg = sl ^ (ww & 7);
            union { signed char b[16]; int4v v; } u;
#pragma unroll
            for (int e = 0; e < 16; ++e)
                u.b[e] = (xs[cg * 16 + e][ww] >= 0.5f) ? 1 : 0;
            *(int4v*)(Op + ww * 128 + sl * 16) = u.v;
        }
    }
}

// ---------------------------------------------------------------------------
// Fused conv3x3 SAME + BN + PLIF (+residual), i8 MFMA, one-period-deep
// register pipeline: STAGEB(g+2) issued at period start; b/a fragments for
// period g+1 are ds_read DURING period g's MFMA cluster (in-place regs).
// 2 barriers/period; every period ends lgkm-drained (buffer write safety).
// Block = (b, row-pair): 512 thr / 8 waves = 2 rows x 4 co-quarters.
// MODE 0: out = spikes i8 NHWC swizzled.  MODE 1: out = spike + x, fp32 NCHW.
// ---------------------------------------------------------------------------
template<int MODE>
__global__ __launch_bounds__(512) void convplif_k(
        const signed char* __restrict__ Xin,  // i8 NHWC swizzled [32][3136][128]
        const signed char* __restrict__ Bs,   // 27 x 16KB tiles (tap*3+sp)
        const float* __restrict__ sv,
        const float* __restrict__ gamma, const float* __restrict__ beta,
        const float* __restrict__ mean,  const float* __restrict__ var,
        const float* __restrict__ tau,
        const float* __restrict__ xres,       // MODE1: residual input x
        void* __restrict__ outp) {
    __shared__ signed char aA[4 * APITCH];    // 4 row-slots, zero-padded px slots
    __shared__ signed char bB[2][49152];      // tap dbuf: 3 split tiles each
    __shared__ signed char sS[2 * 8192];      // spike repack scratch (MODE0)

    const int tid = threadIdx.x;
    const int lane = tid & 63;
    const int wave = tid >> 6;
    const int fr = lane & 15, fq = lane >> 4;
    const int row_local = wave >> 2;          // 0..1
    const int q = wave & 3;                   // co-quarter
    const int bb = blockIdx.x / 28;           // batch index
    const int h0 = (blockIdx.x % 28) * 2;
    const int h = h0 + row_local;
    const int tap0 = (int)((blockIdx.x * 4u) % 9u);
    const int nA = (h0 == 0 || h0 == 54) ? 3 : 4;

    const float kk = 1.f / (1.f + expf(-tau[0]));
    float mulv[2], bsv[2];
#pragma unroll
    for (int nf = 0; nf < 2; ++nf) {
        int co = q * 32 + nf * 16 + fr;
        float iv = gamma[co] / sqrtf(var[co] + 1e-5f);
        mulv[nf] = sv[co] * iv;
        bsv[nf] = beta[co] - mean[co] * iv;
    }

    const int4v zi = (int4v){0, 0, 0, 0};

#define STAGEA(tt) do {                                                           \
        const signed char* _XtN = Xin + (size_t)((tt) * 8 + bb) * (HW * 128);     \
        if (tid < 448) {                                                          \
            _Pragma("unroll")                                                     \
            for (int _i = 0; _i < 4; ++_i) {                                      \
                int _hh = h0 - 1 + _i;                                            \
                if ((unsigned)_hh < 56u)                                          \
                    GLOAD_LDS16((const char*)(_XtN + (size_t)_hh * 7168) + tid * 16, \
                                (char*)aA + _i * APITCH + 128 + tid * 16);        \
            }                                                                     \
        }                                                                         \
    } while (0)

#define STAGEB(tp, buf) do {                                                      \
        const char* _src = (const char*)Bs + (size_t)(tp) * 49152 + tid * 16;     \
        char* _dst = (char*)&bB[(buf)][0] + tid * 16;                             \
        _Pragma("unroll")                                                         \
        for (int _c = 0; _c < 6; ++_c)                                            \
            GLOAD_LDS16(_src + _c * 8192, _dst + _c * 8192);                      \
    } while (0)

    // pure loads, no masks: pad slots are zero
#define LOADA(tp) do {                                                            \
        const int _dh = (tp) / 3, _dw = (tp) - ((tp) / 3) * 3;                    \
        const signed char* _rb = aA + (row_local + _dh) * APITCH;                 \
        _Pragma("unroll")                                                         \
        for (int _m = 0; _m < 4; ++_m) {                                          \
            int _px1 = _m * 16 + fr + _dw;                                        \
            int _k7 = (_px1 - 1) & 7;                                             \
            const signed char* _bp = _rb + _px1 * 128;                            \
            a[_m][0] = *(const int4v*)(_bp + ((fq ^ _k7) << 4));                  \
            a[_m][1] = *(const int4v*)(_bp + (((4 + fq) ^ _k7) << 4));            \
        }                                                                         \
    } while (0)

    // ---- prologue: zero pads; stage A(0), B(tap0)->buf0, B(tap0+1)->buf1 ----
    for (int j = tid; j < 320; j += 512) {
        int row = j / 80, off = j - (j / 80) * 80;
        int byte = row * APITCH + (off < 8 ? off * 16 : 7296 + (off - 8) * 16);
        *(int4v*)((char*)aA + byte) = zi;
    }
    if (h0 == 0)
        for (int j = tid; j < 528; j += 512) *(int4v*)((char*)aA + j * 16) = zi;
    if (h0 == 54)
        for (int j = tid; j < 528; j += 512) *(int4v*)((char*)aA + 3 * APITCH + j * 16) = zi;
    STAGEA(0);
    STAGEB(tap0, 0);
    STAGEB((tap0 + 1) % 9, 1);
    asm volatile("s_waitcnt vmcnt(0) lgkmcnt(0)" ::: "memory");
    __builtin_amdgcn_sched_barrier(0);
    __builtin_amdgcn_s_barrier();

    int4v acc[3][4][2];
#pragma unroll
    for (int sp = 0; sp < 3; ++sp)
#pragma unroll
        for (int m = 0; m < 4; ++m) { acc[sp][m][0] = zi; acc[sp][m][1] = zi; }
    float v[2][4][4];
#pragma unroll
    for (int nf = 0; nf < 2; ++nf)
#pragma unroll
        for (int m = 0; m < 4; ++m)
#pragma unroll
            for (int r = 0; r < 4; ++r) v[nf][m][r] = 0.f;

    const int cob = (q * 32 + fr) * 128;
    const int sl0 = (fq ^ (fr & 7)) << 4;
    const int sl1 = ((4 + fq) ^ (fr & 7)) << 4;

    int4v a[4][2];
    int4v b[3][4];                            // [sp][2*nf+ks] current-period frags
    LOADA(tap0);
    {
        const signed char* bbase = &bB[0][0];
#pragma unroll
        for (int sp = 0; sp < 3; ++sp) {
            const signed char* bp = bbase + sp * 16384;
            b[sp][0] = *(const int4v*)(bp + cob + sl0);
            b[sp][1] = *(const int4v*)(bp + cob + sl1);
            b[sp][2] = *(const int4v*)(bp + cob + 2048 + sl0);
            b[sp][3] = *(const int4v*)(bp + cob + 2048 + sl1);
        }
    }
    // prologue reads must retire before g=0 overwrites buf0
    asm volatile("s_waitcnt lgkmcnt(0)" ::: "memory");
    __builtin_amdgcn_sched_barrier(0);
    __builtin_amdgcn_s_barrier();

    // ---- 36 periods ----
    for (int g = 0; g < 36; ++g) {
        const int t = g / 9;
        const int it = g - t * 9;             // 0..8
        const bool tend = (it == 8);
        const int tap = (tap0 + g) % 9;
        const int ntap = (tap + 1 == 9) ? 0 : tap + 1;

        // step 2: issue DMA (A first so vmcnt counts stay uniform)
        if (tend && t < 3) STAGEA(t + 1);
        if (g <= 33) STAGEB((tap0 + g + 2) % 9, g & 1);

        // step 3: retire B(g+1) (+A at t-boundary), leave B(g+2) in flight
        if (g >= 34) {
            asm volatile("s_waitcnt vmcnt(0)" ::: "memory");
        } else if (tend && t < 3) {
            if (tid < 448) {
                if (nA == 4) asm volatile("s_waitcnt vmcnt(10)" ::: "memory");
                else         asm volatile("s_waitcnt vmcnt(9)"  ::: "memory");
            } else {
                asm volatile("s_waitcnt vmcnt(6)" ::: "memory");
            }
        } else {
            asm volatile("s_waitcnt vmcnt(6)" ::: "memory");
        }
        __builtin_amdgcn_sched_barrier(0);
        __builtin_amdgcn_s_barrier();          // barrier 1: staged data visible

        if (it == 0 && g > 0) LOADA(tap);      // fresh A(t): front-load a-frags

        const bool datail = (it != 8) && (g < 35);
        const bool dbtail = (g < 35);
        const int ndh = ntap / 3, ndw = ntap - ndh * 3;
        const signed char* nrb = aA + (row_local + ndh) * APITCH;
        const signed char* nb = &bB[(g + 1) & 1][0];

        __builtin_amdgcn_s_setprio(1);
#pragma unroll
        for (int sp = 0; sp < 3; ++sp) {
#pragma unroll
            for (int m = 0; m < 4; ++m) {
                acc[sp][m][0] = __builtin_amdgcn_mfma_i32_16x16x64_i8(a[m][0], b[sp][0], acc[sp][m][0], 0, 0, 0);
                acc[sp][m][0] = __builtin_amdgcn_mfma_i32_16x16x64_i8(a[m][1], b[sp][1], acc[sp][m][0], 0, 0, 0);
                acc[sp][m][1] = __builtin_amdgcn_mfma_i32_16x16x64_i8(a[m][0], b[sp][2], acc[sp][m][1], 0, 0, 0);
                acc[sp][m][1] = __builtin_amdgcn_mfma_i32_16x16x64_i8(a[m][1], b[sp][3], acc[sp][m][1], 0, 0, 0);
                if (sp == 2 && datail) {       // a[m] free: prefetch next tap
                    int px1 = m * 16 + fr + ndw;
                    int k7 = (px1 - 1) & 7;
                    const signed char* bp2 = nrb + px1 * 128;
                    a[m][0] = *(const int4v*)(bp2 + ((fq ^ k7) << 4));
                    a[m][1] = *(const int4v*)(bp2 + (((4 + fq) ^ k7) << 4));
                }
            }
            if (dbtail) {                      // b[sp] free: prefetch next period
                const signed char* bp2 = nb + sp * 16384;
                b[sp][0] = *(const int4v*)(bp2 + cob + sl0);
                b[sp][1] = *(const int4v*)(bp2 + cob + sl1);
                b[sp][2] = *(const int4v*)(bp2 + cob + 2048 + sl0);
                b[sp][3] = *(const int4v*)(bp2 + cob + 2048 + sl1);
            }
        }
        __builtin_amdgcn_s_setprio(0);

        // drain this period's ds_reads, then sync: next period may overwrite
        asm volatile("s_waitcnt lgkmcnt(0)" ::: "memory");
        __builtin_amdgcn_sched_barrier(0);
        __builtin_amdgcn_s_barrier();          // barrier 2: write safety

        if (tend) {
            // ---- per-t epilogue: fold + BN + PLIF (+store) ----
            if (MODE == 0) {
                signed char* S1 = (signed char*)outp;
#pragma unroll
                for (int nf = 0; nf < 2; ++nf)
#pragma unroll
                    for (int m = 0; m < 4; ++m)
#pragma unroll
                        for (int r = 0; r < 4; ++r) {
                            int px = m * 16 + fq * 4 + r;
                            float val = (float)acc[0][m][nf][r]
                                      + (float)acc[1][m][nf][r] * 0.0078125f
                                      + (float)acc[2][m][nf][r] * 6.103515625e-05f;
                            float y = fmaf(val, mulv[nf], bsv[nf]);
                            float vv = v[nf][m][r];
                            vv = vv + (y - vv) * kk;
                            bool spk = vv >= 1.f;
                            v[nf][m][r] = spk ? 0.f : vv;
                            sS[row_local * 8192 + px * 128 + q * 32 + nf * 16 + fr] = spk ? 1 : 0;
                        }
                asm volatile("s_waitcnt lgkmcnt(0)" ::: "memory");
                __builtin_amdgcn_s_barrier();
                const size_t imgb = (size_t)(t * 8 + bb) * HW;
#pragma unroll
                for (int cc = 0; cc < 2; ++cc) {
                    int chunk = tid + cc * 512;
                    int row = chunk >> 9, rem = chunk & 511;
                    int px = rem >> 3, cg = rem & 7;
                    if (px < 56) {
                        int4v v16 = *(const int4v*)(sS + row * 8192 + px * 128 + cg * 16);
                        *(int4v*)(S1 + (imgb + (size_t)(h0 + row) * 56 + px) * 128
                                     + ((cg ^ (px & 7)) << 4)) = v16;
                    }
                }
                __builtin_amdgcn_s_barrier();  // sS reads done before next t's writes
            } else {
                float* outw = (float*)outp;
#pragma unroll
                for (int nf = 0; nf < 2; ++nf) {
                    const size_t cobase = ((size_t)(t * 8 + bb) * 128 + q * 32 + nf * 16 + fr) * HW
                                        + (size_t)h * 56;
#pragma unroll
                    for (int m = 0; m < 4; ++m) {
                        int px0 = m * 16 + fq * 4;
                        float o4[4];
#pragma unroll
                        for (int r = 0; r < 4; ++r) {
                            float val = (float)acc[0][m][nf][r]
                                      + (float)acc[1][m][nf][r] * 0.0078125f
                                      + (float)acc[2][m][nf][r] * 6.103515625e-05f;
                            float y = fmaf(val, mulv[nf], bsv[nf]);
                            float vv = v[nf][m][r];
                            vv = vv + (y - vv) * kk;
                            bool spk = vv >= 1.f;
                            v[nf][m][r] = spk ? 0.f : vv;
                            o4[r] = spk ? 1.f : 0.f;
                        }
                        if (px0 < 56) {
                            float4 xv = *(const float4*)(xres + cobase + px0);
                            float4 ov = make_float4(o4[0] + xv.x, o4[1] + xv.y,
                                                    o4[2] + xv.z, o4[3] + xv.w);
                            *(float4*)(outw + cobase + px0) = ov;
                        }
                    }
                }
            }
#pragma unroll
            for (int sp = 0; sp < 3; ++sp)
#pragma unroll
                for (int m = 0; m < 4; ++m) { acc[sp][m][0] = zi; acc[sp][m][1] = zi; }
        }
    }
#undef STAGEA
#undef STAGEB
#undef LOADA
}

// ---------------------------------------------------------------------------
extern "C" void kernel_launch(void* const* d_in, const int* in_sizes, int n_in,
                              void* d_out, int out_size, void* d_ws, size_t ws_size,
                              hipStream_t stream) {
    const float* x    = (const float*)d_in[0];
    const float* w1   = (const float*)d_in[1];
    const float* g1   = (const float*)d_in[2];
    const float* be1  = (const float*)d_in[3];
    const float* mu1  = (const float*)d_in[4];
    const float* va1  = (const float*)d_in[5];
    const float* tau1 = (const float*)d_in[6];
    const float* w2   = (const float*)d_in[7];
    const float* g2   = (const float*)d_in[8];
    const float* be2  = (const float*)d_in[9];
    const float* mu2  = (const float*)d_in[10];
    const float* va2  = (const float*)d_in[11];
    const float* tau2 = (const float*)d_in[12];
    float* out = (float*)d_out;

    char* ws = (char*)d_ws;
    signed char* Xt  = (signed char*)ws;           // i8 [NE]
    signed char* S1  = (signed char*)(ws + NE);    // i8 [NE]
    float* sv1  = (float*)(ws + 2 * NE);
    float* sv2  = sv1 + 128;
    signed char* Bs1 = (signed char*)(ws + 2 * NE + 1024);
    signed char* Bs2 = Bs1 + 27 * 16384;

    scale_k<<<128, 128, 0, stream>>>(w1, sv1);
    scale_k<<<128, 128, 0, stream>>>(w2, sv2);
    repack_k<<<36, 256, 0, stream>>>(w1, sv1, Bs1);
    repack_k<<<36, 256, 0, stream>>>(w2, sv2, Bs2);
    xpose_k<<<NIMG * 56, 256, 0, stream>>>(x, Xt);

    convplif_k<0><<<B_ * 28, 512, 0, stream>>>(Xt, Bs1, sv1, g1, be1, mu1, va1,
                                               tau1, x, (void*)S1);
    convplif_k<1><<<B_ * 28, 512, 0, stream>>>(S1, Bs2, sv2, g2, be2, mu2, va2,
                                               tau2, x, (void*)out);
}